// Round 7
// baseline (1300.783 us; speedup 1.0000x reference)
//
#include <hip/hip_runtime.h>
#include <stdint.h>

// Problem constants (B=4, S=2048 -> T=8192 tokens)
#define T_TOK 8192
#define DIM   1024
#define NEXP  8
#define HID   2816

typedef __bf16 bf16x8 __attribute__((ext_vector_type(8)));
typedef float  f32x4  __attribute__((ext_vector_type(4)));

typedef __attribute__((address_space(3))) uint32_t lds_u32_t;
typedef __attribute__((address_space(1))) const uint32_t gbl_u32_t;

// async global->LDS, 16B per lane. LDS dest = wave-uniform base + lane*16.
__device__ __forceinline__ void gl_lds16(const void* g, void* l) {
    __builtin_amdgcn_global_load_lds((gbl_u32_t*)g, (lds_u32_t*)l, 16, 0, 0);
}

__device__ __forceinline__ uint32_t f2bf_u(float f) {
    uint32_t u = __builtin_bit_cast(uint32_t, f);
    return u + 0x7fffu + ((u >> 16) & 1u);   // RNE to bf16, top 16 bits valid
}
__device__ __forceinline__ uint32_t pack2(float a, float b) {
    return (f2bf_u(a) >> 16) | (f2bf_u(b) & 0xffff0000u);
}

// ---------------------------------------------------------------------------
// Structure (round 7): B operands (w1/w3/w2 rows) load DIRECTLY global->VGPR,
// bypassing LDS. Rationale: rounds 2/4/5 proved schedule changes don't move
// ffn1 (255-275us, MfmaUtil ~34%) because the LDS pipe serializes:
// 48KB/block-kstep (A+B, write+read) at ~112B/cyc ~= 430cyc >> 80cyc MFMA.
// Weights are L2-served (L2 pipe 22% busy). LDS traffic halves (A only).
// SAFETY: after two container failures on hand-vmcnt ledgers (r3/r6), this
// round uses ONLY the proven __syncthreads 2-buffer pipeline (round 4 ran):
//   - A (gathered rows, reused by 2 waves): LDS, 2 buffers, stage(t+1)
//     issued before compute(t), one __syncthreads per k-step. Staged by all
//     4 waves (2 gl_lds each). Quarter swizzle (round 2, conflict-free).
//   - B: register double-buffer via 2x-unrolled loop with two NAMED register
//     sets (bA*/bB*) -> static indexing, no copies (rule #20).
// No inline asm except s_setprio (ran in r4/r5).
// ---------------------------------------------------------------------------

// ---------------------------------------------------------------------------
// Kernel 0: fp32 -> bf16 conversion (weights + x), 8 floats/thread.
// ---------------------------------------------------------------------------
__global__ __launch_bounds__(256) void cvt_k(
    const float* __restrict__ s, unsigned short* __restrict__ d, int n8)
{
    int i = blockIdx.x * 256 + threadIdx.x;
    if (i < n8) {
        const float4* sp = (const float4*)(s + (size_t)i * 8);
        float4 a = sp[0], b = sp[1];
        uint4 o;
        o.x = pack2(a.x, a.y); o.y = pack2(a.z, a.w);
        o.z = pack2(b.x, b.y); o.w = pack2(b.z, b.w);
        ((uint4*)d)[i] = o;
    }
}

// ---------------------------------------------------------------------------
// Kernel 1: router. One wave per token, fp64 logits, top-2 + softmax,
// per-expert gather lists via atomic counters.
// ---------------------------------------------------------------------------
__global__ __launch_bounds__(256) void router_k(
    const float* __restrict__ x, const float* __restrict__ gw,
    int* __restrict__ cnt, int* __restrict__ slot_list,
    float* __restrict__ slot_w)
{
    const int wave = threadIdx.x >> 6, lane = threadIdx.x & 63;
    const int t = blockIdx.x * 4 + wave;
    const float4* xp = (const float4*)(x + (size_t)t * DIM + lane * 16);
    float4 xv[4];
#pragma unroll
    for (int i = 0; i < 4; ++i) xv[i] = xp[i];

    double lg[NEXP];
#pragma unroll
    for (int e = 0; e < NEXP; ++e) {
        const float4* gp = (const float4*)(gw + (size_t)e * DIM + lane * 16);
        double s = 0.0;
#pragma unroll
        for (int i = 0; i < 4; ++i) {
            float4 g = gp[i];
            s += (double)xv[i].x * g.x + (double)xv[i].y * g.y +
                 (double)xv[i].z * g.z + (double)xv[i].w * g.w;
        }
#pragma unroll
        for (int m = 32; m >= 1; m >>= 1) s += __shfl_xor(s, m, 64);
        lg[e] = s;
    }

    if (lane == 0) {
        int e0 = 0; double b0 = lg[0];
#pragma unroll
        for (int e = 1; e < NEXP; ++e)
            if (lg[e] > b0) { b0 = lg[e]; e0 = e; }
        int e1 = -1; double b1 = -1.0e300;
#pragma unroll
        for (int e = 0; e < NEXP; ++e)
            if (e != e0 && lg[e] > b1) { b1 = lg[e]; e1 = e; }

        float p0 = (float)(1.0 / (1.0 + exp(b1 - b0)));
        float p1 = 1.0f - p0;

        int pos0 = atomicAdd(&cnt[e0], 1);
        slot_list[e0 * T_TOK + pos0] = 2 * t;
        slot_w[2 * t] = p0;
        int pos1 = atomicAdd(&cnt[e1], 1);
        slot_list[e1 * T_TOK + pos1] = 2 * t + 1;
        slot_w[2 * t + 1] = p1;
    }
}

// ---------------------------------------------------------------------------
// Kernel 2: gathered GEMM, fused w1/w3 + SwiGLU. C-tile 128 slots x (64+64).
// grid (HID/64=44, ceilT/128, NEXP), early-exit on empty m-block.
// ---------------------------------------------------------------------------
__global__ __launch_bounds__(256) void ffn1_k(
    const unsigned short* __restrict__ xb, const unsigned short* __restrict__ w1b,
    const unsigned short* __restrict__ w3b, const int* __restrict__ cnt,
    const int* __restrict__ slot_list, unsigned short* __restrict__ h_ws)
{
    __shared__ unsigned short As[2][128 * 32];   // 16 KB
    __shared__ int slots_s[128];

    const int e = blockIdx.z;
    const int cntE = cnt[e];
    const int m0 = blockIdx.y * 128;
    if (m0 >= cntE) return;
    const int n0 = blockIdx.x * 64;
    const int tid = threadIdx.x;
    const int wave = tid >> 6, lane = tid & 63;

    if (tid < 128) {
        int idx = m0 + tid;
        slots_s[tid] = (idx < cntE) ? slot_list[e * T_TOK + idx] : -1;
    }
    __syncthreads();

    // A staging: 2 gl_lds per wave per k-step; wave w covers rows w*32..+31.
    // Lane l: row rr=l>>2 within its 16-row instr, physical quarter p=l&3,
    // global chunk qsw = p ^ ((rr>>1)&3) (swizzle within the 64B row chunk;
    // coalescing = 16 rows x 64B per instr, unchanged).
    const int rr = lane >> 2;
    const int qsw = (lane & 3) ^ ((rr >> 1) & 3);
    const unsigned short* gsrc[2];
    unsigned short* ldst[2];
    const int bstride = 128 * 32;
#pragma unroll
    for (int i = 0; i < 2; ++i) {
        int row = wave * 32 + i * 16 + rr;
        int slot = slots_s[row];
        int tok = (slot >= 0) ? (slot >> 1) : 0;   // clamp tail to token 0
        gsrc[i] = xb + (size_t)tok * DIM + qsw * 8;
        ldst[i] = &As[0][(wave * 32 + i * 16) * 32];
    }

    const int wm = wave >> 1, wn = wave & 1;
    const int lrow = lane & 15, quad = lane >> 4;
    const int ksw = (quad ^ ((lrow >> 1) & 3)) * 8;   // swizzled k-offset (A)

    // B direct-load bases: lane reads row (n0+wn*32+ni*16+lrow) of w1/w3 at
    // k-chunk quad*8 -> logically identical fragment to the old LDS read.
    const unsigned short* w1p =
        w1b + ((size_t)e * HID + n0 + wn * 32 + lrow) * DIM + quad * 8;
    const unsigned short* w3p =
        w3b + ((size_t)e * HID + n0 + wn * 32 + lrow) * DIM + quad * 8;

    f32x4 acc1[4][2], acc2[4][2];
    const f32x4 zf = {0.f, 0.f, 0.f, 0.f};
#pragma unroll
    for (int mi = 0; mi < 4; ++mi)
#pragma unroll
        for (int ni = 0; ni < 2; ++ni) { acc1[mi][ni] = zf; acc2[mi][ni] = zf; }

    const int NST = DIM / 32;   // 32 k-steps (even)

    bf16x8 bA10, bA11, bA30, bA31;   // B regs, even iterations
    bf16x8 bB10, bB11, bB30, bB31;   // B regs, odd iterations

    // prologue: stage A(0)->buf0; load B(0)->bA; sync.
#pragma unroll
    for (int i = 0; i < 2; ++i) { gl_lds16(gsrc[i], ldst[i]); gsrc[i] += 32; }
    bA10 = *(const bf16x8*)(w1p);
    bA11 = *(const bf16x8*)(w1p + 16 * DIM);
    bA30 = *(const bf16x8*)(w3p);
    bA31 = *(const bf16x8*)(w3p + 16 * DIM);
    w1p += 32; w3p += 32;
    __syncthreads();

    for (int t = 0; t < NST; t += 2) {
        // ---- even sub-iter: compute buf0/bA; prefetch (t+1)->buf1/bB ----
        {
#pragma unroll
            for (int i = 0; i < 2; ++i) {
                gl_lds16(gsrc[i], ldst[i] + bstride); gsrc[i] += 32;
            }
            bB10 = *(const bf16x8*)(w1p);
            bB11 = *(const bf16x8*)(w1p + 16 * DIM);
            bB30 = *(const bf16x8*)(w3p);
            bB31 = *(const bf16x8*)(w3p + 16 * DIM);
            w1p += 32; w3p += 32;

            const unsigned short* Ab = &As[0][0];
            bf16x8 af[4];
#pragma unroll
            for (int mi = 0; mi < 4; ++mi)
                af[mi] = *(const bf16x8*)&Ab[(wm * 64 + mi * 16 + lrow) * 32 + ksw];
            __builtin_amdgcn_s_setprio(1);
#pragma unroll
            for (int mi = 0; mi < 4; ++mi) {
                acc1[mi][0] = __builtin_amdgcn_mfma_f32_16x16x32_bf16(
                    af[mi], bA10, acc1[mi][0], 0, 0, 0);
                acc1[mi][1] = __builtin_amdgcn_mfma_f32_16x16x32_bf16(
                    af[mi], bA11, acc1[mi][1], 0, 0, 0);
                acc2[mi][0] = __builtin_amdgcn_mfma_f32_16x16x32_bf16(
                    af[mi], bA30, acc2[mi][0], 0, 0, 0);
                acc2[mi][1] = __builtin_amdgcn_mfma_f32_16x16x32_bf16(
                    af[mi], bA31, acc2[mi][1], 0, 0, 0);
            }
            __builtin_amdgcn_s_setprio(0);
            __syncthreads();
        }
        // ---- odd sub-iter: compute buf1/bB; prefetch (t+2)->buf0/bA ----
        {
            const bool more = (t + 2 < NST);
            if (more) {
#pragma unroll
                for (int i = 0; i < 2; ++i) {
                    gl_lds16(gsrc[i], ldst[i]); gsrc[i] += 32;
                }
                bA10 = *(const bf16x8*)(w1p);
                bA11 = *(const bf16x8*)(w1p + 16 * DIM);
                bA30 = *(const bf16x8*)(w3p);
                bA31 = *(const bf16x8*)(w3p + 16 * DIM);
                w1p += 32; w3p += 32;
            }
            const unsigned short* Ab = &As[1][0];
            bf16x8 af[4];
#pragma unroll
            for (int mi = 0; mi < 4; ++mi)
                af[mi] = *(const bf16x8*)&Ab[(wm * 64 + mi * 16 + lrow) * 32 + ksw];
            __builtin_amdgcn_s_setprio(1);
#pragma unroll
            for (int mi = 0; mi < 4; ++mi) {
                acc1[mi][0] = __builtin_amdgcn_mfma_f32_16x16x32_bf16(
                    af[mi], bB10, acc1[mi][0], 0, 0, 0);
                acc1[mi][1] = __builtin_amdgcn_mfma_f32_16x16x32_bf16(
                    af[mi], bB11, acc1[mi][1], 0, 0, 0);
                acc2[mi][0] = __builtin_amdgcn_mfma_f32_16x16x32_bf16(
                    af[mi], bB30, acc2[mi][0], 0, 0, 0);
                acc2[mi][1] = __builtin_amdgcn_mfma_f32_16x16x32_bf16(
                    af[mi], bB31, acc2[mi][1], 0, 0, 0);
            }
            __builtin_amdgcn_s_setprio(0);
            if (more) __syncthreads();
        }
    }

    // epilogue: h = silu(a1) * a3 -> bf16 h_ws[slot, n]
#pragma unroll
    for (int mi = 0; mi < 4; ++mi) {
#pragma unroll
        for (int r = 0; r < 4; ++r) {
            int mloc = wm * 64 + mi * 16 + quad * 4 + r;
            int slot = slots_s[mloc];
            if (slot >= 0) {
                unsigned short* hrow =
                    h_ws + (size_t)slot * HID + n0 + wn * 32 + lrow;
#pragma unroll
                for (int ni = 0; ni < 2; ++ni) {
                    float a1 = acc1[mi][ni][r], a3 = acc2[mi][ni][r];
                    float hv = (a1 / (1.f + __expf(-a1))) * a3;
                    hrow[ni * 16] = (unsigned short)(f2bf_u(hv) >> 16);
                }
            }
        }
    }
}

// ---------------------------------------------------------------------------
// Kernel 3: gathered GEMM y = h @ w2^T, scale by routing weight, atomicAdd
// into out. C-tile 128 x 128. A (gathered h) via LDS 2-buffer pipeline; w2
// direct to regs (2x-unrolled double-buffer). grid (DIM/128=8, ceilT/128, 8).
// ---------------------------------------------------------------------------
__global__ __launch_bounds__(256) void ffn2_k(
    const unsigned short* __restrict__ h_ws, const unsigned short* __restrict__ w2b,
    const int* __restrict__ cnt, const int* __restrict__ slot_list,
    const float* __restrict__ slot_w, float* __restrict__ out)
{
    __shared__ unsigned short As[2][128 * 32];   // 16 KB
    __shared__ int slots_s[128];
    __shared__ float wgt_s[128];

    const int e = blockIdx.z;
    const int cntE = cnt[e];
    const int m0 = blockIdx.y * 128;
    if (m0 >= cntE) return;
    const int n0 = blockIdx.x * 128;
    const int tid = threadIdx.x;
    const int wave = tid >> 6, lane = tid & 63;

    if (tid < 128) {
        int idx = m0 + tid;
        int s = (idx < cntE) ? slot_list[e * T_TOK + idx] : -1;
        slots_s[tid] = s;
        wgt_s[tid] = (s >= 0) ? slot_w[s] : 0.f;
    }
    __syncthreads();

    const int rr = lane >> 2;
    const int qsw = (lane & 3) ^ ((rr >> 1) & 3);
    const unsigned short* gsrc[2];
    unsigned short* ldst[2];
    const int bstride = 128 * 32;
#pragma unroll
    for (int i = 0; i < 2; ++i) {
        int row = wave * 32 + i * 16 + rr;
        int slot = slots_s[row];
        int s = (slot >= 0) ? slot : 0;
        gsrc[i] = h_ws + (size_t)s * HID + qsw * 8;
        ldst[i] = &As[0][(wave * 32 + i * 16) * 32];
    }

    const int wm = wave >> 1, wn = wave & 1;
    const int lrow = lane & 15, quad = lane >> 4;
    const int ksw = (quad ^ ((lrow >> 1) & 3)) * 8;

    // w2 direct-load base: rows n0 + wn*64 + ni*16 + lrow, k-chunk quad*8.
    const unsigned short* w2p =
        w2b + ((size_t)e * DIM + n0 + wn * 64 + lrow) * HID + quad * 8;

    f32x4 acc[4][4];
    const f32x4 zf = {0.f, 0.f, 0.f, 0.f};
#pragma unroll
    for (int mi = 0; mi < 4; ++mi)
#pragma unroll
        for (int ni = 0; ni < 4; ++ni) acc[mi][ni] = zf;

    const int NST = HID / 32;   // 88 k-steps (even)

    bf16x8 bA0, bA1, bA2, bA3;
    bf16x8 bB0, bB1, bB2, bB3;

    // prologue: stage A(0)->buf0; load B(0)->bA; sync.
#pragma unroll
    for (int i = 0; i < 2; ++i) { gl_lds16(gsrc[i], ldst[i]); gsrc[i] += 32; }
    bA0 = *(const bf16x8*)(w2p);
    bA1 = *(const bf16x8*)(w2p + 16 * HID);
    bA2 = *(const bf16x8*)(w2p + 32 * HID);
    bA3 = *(const bf16x8*)(w2p + 48 * HID);
    w2p += 32;
    __syncthreads();

    for (int t = 0; t < NST; t += 2) {
        // ---- even sub-iter: compute buf0/bA; prefetch (t+1)->buf1/bB ----
        {
#pragma unroll
            for (int i = 0; i < 2; ++i) {
                gl_lds16(gsrc[i], ldst[i] + bstride); gsrc[i] += 32;
            }
            bB0 = *(const bf16x8*)(w2p);
            bB1 = *(const bf16x8*)(w2p + 16 * HID);
            bB2 = *(const bf16x8*)(w2p + 32 * HID);
            bB3 = *(const bf16x8*)(w2p + 48 * HID);
            w2p += 32;

            const unsigned short* Ab = &As[0][0];
            bf16x8 af[4];
#pragma unroll
            for (int mi = 0; mi < 4; ++mi)
                af[mi] = *(const bf16x8*)&Ab[(wm * 64 + mi * 16 + lrow) * 32 + ksw];
            __builtin_amdgcn_s_setprio(1);
#pragma unroll
            for (int mi = 0; mi < 4; ++mi) {
                acc[mi][0] = __builtin_amdgcn_mfma_f32_16x16x32_bf16(
                    af[mi], bA0, acc[mi][0], 0, 0, 0);
                acc[mi][1] = __builtin_amdgcn_mfma_f32_16x16x32_bf16(
                    af[mi], bA1, acc[mi][1], 0, 0, 0);
                acc[mi][2] = __builtin_amdgcn_mfma_f32_16x16x32_bf16(
                    af[mi], bA2, acc[mi][2], 0, 0, 0);
                acc[mi][3] = __builtin_amdgcn_mfma_f32_16x16x32_bf16(
                    af[mi], bA3, acc[mi][3], 0, 0, 0);
            }
            __builtin_amdgcn_s_setprio(0);
            __syncthreads();
        }
        // ---- odd sub-iter: compute buf1/bB; prefetch (t+2)->buf0/bA ----
        {
            const bool more = (t + 2 < NST);
            if (more) {
#pragma unroll
                for (int i = 0; i < 2; ++i) {
                    gl_lds16(gsrc[i], ldst[i]); gsrc[i] += 32;
                }
                bA0 = *(const bf16x8*)(w2p);
                bA1 = *(const bf16x8*)(w2p + 16 * HID);
                bA2 = *(const bf16x8*)(w2p + 32 * HID);
                bA3 = *(const bf16x8*)(w2p + 48 * HID);
                w2p += 32;
            }
            const unsigned short* Ab = &As[1][0];
            bf16x8 af[4];
#pragma unroll
            for (int mi = 0; mi < 4; ++mi)
                af[mi] = *(const bf16x8*)&Ab[(wm * 64 + mi * 16 + lrow) * 32 + ksw];
            __builtin_amdgcn_s_setprio(1);
#pragma unroll
            for (int mi = 0; mi < 4; ++mi) {
                acc[mi][0] = __builtin_amdgcn_mfma_f32_16x16x32_bf16(
                    af[mi], bB0, acc[mi][0], 0, 0, 0);
                acc[mi][1] = __builtin_amdgcn_mfma_f32_16x16x32_bf16(
                    af[mi], bB1, acc[mi][1], 0, 0, 0);
                acc[mi][2] = __builtin_amdgcn_mfma_f32_16x16x32_bf16(
                    af[mi], bB2, acc[mi][2], 0, 0, 0);
                acc[mi][3] = __builtin_amdgcn_mfma_f32_16x16x32_bf16(
                    af[mi], bB3, acc[mi][3], 0, 0, 0);
            }
            __builtin_amdgcn_s_setprio(0);
            if (more) __syncthreads();
        }
    }

#pragma unroll
    for (int mi = 0; mi < 4; ++mi) {
#pragma unroll
        for (int r = 0; r < 4; ++r) {
            int mloc = wm * 64 + mi * 16 + quad * 4 + r;
            int slot = slots_s[mloc];
            if (slot >= 0) {
                int tok = slot >> 1;
                float w = wgt_s[mloc];
                float* orow = out + (size_t)tok * DIM + n0 + wn * 64 + lrow;
#pragma unroll
                for (int ni = 0; ni < 4; ++ni)
                    atomicAdd(&orow[ni * 16], acc[mi][ni][r] * w);
            }
        }
    }
}

// ---------------------------------------------------------------------------
// Workspace layout (bytes, all 256-aligned):
//   [0, 256)                 cnt[8]                (memset 0 per launch)
//   [256, +262144)           slot_list[8][8192]
//   [+262144, +65536)        slot_w[16384]
//   [327936, +92274688)      h_ws   bf16 [16384][2816]
//   [92602624, +16777216)    x_bf   bf16 [8192][1024]
//   [109379840, +46137344)   w1_bf  bf16 [8][2816][1024]
//   [155517184, +46137344)   w3_bf
//   [201654528, +46137344)   w2_bf  bf16 [8][1024][2816]
//   total ~247.8 MB
// ---------------------------------------------------------------------------
extern "C" void kernel_launch(void* const* d_in, const int* in_sizes, int n_in,
                              void* d_out, int out_size, void* d_ws, size_t ws_size,
                              hipStream_t stream) {
    const float* x  = (const float*)d_in[0];
    const float* gw = (const float*)d_in[1];
    const float* w1 = (const float*)d_in[2];
    const float* w2 = (const float*)d_in[3];
    const float* w3 = (const float*)d_in[4];
    float* out = (float*)d_out;

    char* ws = (char*)d_ws;
    int*   cnt       = (int*)ws;
    int*   slot_list = (int*)(ws + 256);
    float* slot_w    = (float*)(ws + 256 + NEXP * T_TOK * 4);
    unsigned short* h_ws = (unsigned short*)(ws + 327936);
    unsigned short* x_bf = (unsigned short*)(ws + 92602624);
    unsigned short* w1_bf = (unsigned short*)(ws + 109379840);
    unsigned short* w3_bf = (unsigned short*)(ws + 155517184);
    unsigned short* w2_bf = (unsigned short*)(ws + 201654528);

    hipMemsetAsync(cnt, 0, 256, stream);
    hipMemsetAsync(out, 0, (size_t)T_TOK * DIM * sizeof(float), stream);

    const int nx = T_TOK * DIM / 8;              // 1048576
    const int nw = NEXP * HID * DIM / 8;         // 2883584
    cvt_k<<<(nx + 255) / 256, 256, 0, stream>>>(x, x_bf, nx);
    cvt_k<<<(nw + 255) / 256, 256, 0, stream>>>(w1, w1_bf, nw);
    cvt_k<<<(nw + 255) / 256, 256, 0, stream>>>(w3, w3_bf, nw);
    cvt_k<<<(nw + 255) / 256, 256, 0, stream>>>(w2, w2_bf, nw);

    router_k<<<T_TOK / 4, 256, 0, stream>>>(x, gw, cnt, slot_list, slot_w);
    ffn1_k<<<dim3(HID / 64, T_TOK / 128, NEXP), 256, 0, stream>>>(
        x_bf, w1_bf, w3_bf, cnt, slot_list, h_ws);
    ffn2_k<<<dim3(DIM / 128, T_TOK / 128, NEXP), 256, 0, stream>>>(
        h_ws, w2_bf, cnt, slot_list, slot_w, out);
}

// Round 8
// 899.014 us; speedup vs baseline: 1.4469x; 1.4469x over previous
//
#include <hip/hip_runtime.h>
#include <stdint.h>

// Problem constants (B=4, S=2048 -> T=8192 tokens)
#define T_TOK 8192
#define DIM   1024
#define NEXP  8
#define HID   2816

typedef __bf16 bf16x8 __attribute__((ext_vector_type(8)));
typedef float  f32x4  __attribute__((ext_vector_type(4)));

typedef __attribute__((address_space(3))) uint32_t lds_u32_t;
typedef __attribute__((address_space(1))) const uint32_t gbl_u32_t;

// async global->LDS, 16B per lane. LDS dest = wave-uniform base + lane*16.
__device__ __forceinline__ void gl_lds16(const void* g, void* l) {
    __builtin_amdgcn_global_load_lds((gbl_u32_t*)g, (lds_u32_t*)l, 16, 0, 0);
}

__device__ __forceinline__ uint32_t f2bf_u(float f) {
    uint32_t u = __builtin_bit_cast(uint32_t, f);
    return u + 0x7fffu + ((u >> 16) & 1u);   // RNE to bf16, top 16 bits valid
}
__device__ __forceinline__ uint32_t pack2(float a, float b) {
    return (f2bf_u(a) >> 16) | (f2bf_u(b) & 0xffff0000u);
}

// ---------------------------------------------------------------------------
// Round 8 = round-5 GEMM structure (best measured: ffn1 256us) + atomic-free
// ffn2 epilogue.
//  - LDS quarter swizzle (r2, SQ_LDS_BANK_CONFLICT=0): physical quarter p of
//    row r holds global chunk p ^ ((r>>1)&3); write-side permutation stays
//    within each row's 64B chunk (coalescing preserved), read-side
//    ds_read_b128 is 2-way-bank = free.
//  - K-loop: 3 LDS buffers, depth-2 counted vmcnt (stage t+2 | compute t |
//    vmcnt(4) barrier) — ran clean in r5.
//  - ffn2 NEW: every slot (expert,token) is owned by exactly one lane (TOPK=2
//    gather lists are disjoint), so the 16.7M f32 atomicAdds are replaced by
//    plain stores into y_ws[slot][DIM], then combine_k: out[t]=y[2t]+y[2t+1].
//    y_ws (67MB f32) aliases x_bf+w1_bf(+4MB of w3_bf): those are dead once
//    ffn1 completes; stream order serializes ffn1 -> ffn2 -> combine -> next
//    iteration's cvt rewrites. 'out' memset removed (combine overwrites all).
// Round-7 lesson: B operands must STAY in LDS (B-direct-to-VGPR = 2x
// regression: latency-bound, occupancy drop).
// ---------------------------------------------------------------------------

// ---------------------------------------------------------------------------
// Kernel 0: fp32 -> bf16 conversion (weights + x), 8 floats/thread.
// ---------------------------------------------------------------------------
__global__ __launch_bounds__(256) void cvt_k(
    const float* __restrict__ s, unsigned short* __restrict__ d, int n8)
{
    int i = blockIdx.x * 256 + threadIdx.x;
    if (i < n8) {
        const float4* sp = (const float4*)(s + (size_t)i * 8);
        float4 a = sp[0], b = sp[1];
        uint4 o;
        o.x = pack2(a.x, a.y); o.y = pack2(a.z, a.w);
        o.z = pack2(b.x, b.y); o.w = pack2(b.z, b.w);
        ((uint4*)d)[i] = o;
    }
}

// ---------------------------------------------------------------------------
// Kernel 1: router. One wave per token, fp64 logits, top-2 + softmax,
// per-expert gather lists via atomic counters.
// ---------------------------------------------------------------------------
__global__ __launch_bounds__(256) void router_k(
    const float* __restrict__ x, const float* __restrict__ gw,
    int* __restrict__ cnt, int* __restrict__ slot_list,
    float* __restrict__ slot_w)
{
    const int wave = threadIdx.x >> 6, lane = threadIdx.x & 63;
    const int t = blockIdx.x * 4 + wave;
    const float4* xp = (const float4*)(x + (size_t)t * DIM + lane * 16);
    float4 xv[4];
#pragma unroll
    for (int i = 0; i < 4; ++i) xv[i] = xp[i];

    double lg[NEXP];
#pragma unroll
    for (int e = 0; e < NEXP; ++e) {
        const float4* gp = (const float4*)(gw + (size_t)e * DIM + lane * 16);
        double s = 0.0;
#pragma unroll
        for (int i = 0; i < 4; ++i) {
            float4 g = gp[i];
            s += (double)xv[i].x * g.x + (double)xv[i].y * g.y +
                 (double)xv[i].z * g.z + (double)xv[i].w * g.w;
        }
#pragma unroll
        for (int m = 32; m >= 1; m >>= 1) s += __shfl_xor(s, m, 64);
        lg[e] = s;
    }

    if (lane == 0) {
        int e0 = 0; double b0 = lg[0];
#pragma unroll
        for (int e = 1; e < NEXP; ++e)
            if (lg[e] > b0) { b0 = lg[e]; e0 = e; }
        int e1 = -1; double b1 = -1.0e300;
#pragma unroll
        for (int e = 0; e < NEXP; ++e)
            if (e != e0 && lg[e] > b1) { b1 = lg[e]; e1 = e; }

        float p0 = (float)(1.0 / (1.0 + exp(b1 - b0)));
        float p1 = 1.0f - p0;

        int pos0 = atomicAdd(&cnt[e0], 1);
        slot_list[e0 * T_TOK + pos0] = 2 * t;
        slot_w[2 * t] = p0;
        int pos1 = atomicAdd(&cnt[e1], 1);
        slot_list[e1 * T_TOK + pos1] = 2 * t + 1;
        slot_w[2 * t + 1] = p1;
    }
}

// ---------------------------------------------------------------------------
// Kernel 2: gathered GEMM, fused w1/w3 + SwiGLU. C-tile 128 slots x (64+64).
// grid (HID/64=44, ceilT/128, NEXP), early-exit on empty m-block.
// ---------------------------------------------------------------------------
__global__ __launch_bounds__(256) void ffn1_k(
    const unsigned short* __restrict__ xb, const unsigned short* __restrict__ w1b,
    const unsigned short* __restrict__ w3b, const int* __restrict__ cnt,
    const int* __restrict__ slot_list, unsigned short* __restrict__ h_ws)
{
    __shared__ unsigned short As[3][128 * 32];
    __shared__ unsigned short B1s[3][64 * 32];
    __shared__ unsigned short B2s[3][64 * 32];
    __shared__ int slots_s[128];

    const int e = blockIdx.z;
    const int cntE = cnt[e];
    const int m0 = blockIdx.y * 128;
    if (m0 >= cntE) return;
    const int n0 = blockIdx.x * 64;
    const int tid = threadIdx.x;
    const int wave = tid >> 6, lane = tid & 63;

    if (tid < 128) {
        int idx = m0 + tid;
        slots_s[tid] = (idx < cntE) ? slot_list[e * T_TOK + idx] : -1;
    }
    __syncthreads();

    // staging: 4 global_load_lds per wave per k-step, each instr = 16 rows x
    // 64B coalesced. waves 0,1 -> A (gathered tokens); wave 2 -> w1; wave 3 -> w3.
    const int rr = lane >> 2;
    const int qsw = (lane & 3) ^ ((rr >> 1) & 3);
    const unsigned short* gsrc[4];   // advances to next tile to stage
    unsigned short* ldst[4];         // buffer-0 LDS dest
    int bstride;
    if (wave < 2) {
        bstride = 128 * 32;
#pragma unroll
        for (int i = 0; i < 4; ++i) {
            int row = wave * 64 + i * 16 + rr;
            int slot = slots_s[row];
            int tok = (slot >= 0) ? (slot >> 1) : 0;   // clamp tail to token 0
            gsrc[i] = xb + (size_t)tok * DIM + qsw * 8;
            ldst[i] = &As[0][(wave * 64 + i * 16) * 32];
        }
    } else if (wave == 2) {
        bstride = 64 * 32;
#pragma unroll
        for (int i = 0; i < 4; ++i) {
            int row = i * 16 + rr;
            gsrc[i] = w1b + ((size_t)e * HID + n0 + row) * DIM + qsw * 8;
            ldst[i] = &B1s[0][(i * 16) * 32];
        }
    } else {
        bstride = 64 * 32;
#pragma unroll
        for (int i = 0; i < 4; ++i) {
            int row = i * 16 + rr;
            gsrc[i] = w3b + ((size_t)e * HID + n0 + row) * DIM + qsw * 8;
            ldst[i] = &B2s[0][(i * 16) * 32];
        }
    }

    const int wm = wave >> 1, wn = wave & 1;
    const int lrow = lane & 15, quad = lane >> 4;
    const int ksw = (quad ^ ((lrow >> 1) & 3)) * 8;   // swizzled k-offset

    f32x4 acc1[4][2], acc2[4][2];
    const f32x4 zf = {0.f, 0.f, 0.f, 0.f};
#pragma unroll
    for (int mi = 0; mi < 4; ++mi)
#pragma unroll
        for (int ni = 0; ni < 2; ++ni) { acc1[mi][ni] = zf; acc2[mi][ni] = zf; }

    const int NST = DIM / 32;   // 32 k-steps
    // prologue: stage t=0 -> buf0, t=1 -> buf1; wait t=0 (t=1 stays in flight)
#pragma unroll
    for (int i = 0; i < 4; ++i) gl_lds16(gsrc[i], ldst[i]);
#pragma unroll
    for (int i = 0; i < 4; ++i) gl_lds16(gsrc[i] + 32, ldst[i] + bstride);
#pragma unroll
    for (int i = 0; i < 4; ++i) gsrc[i] += 64;
    asm volatile("s_waitcnt vmcnt(4)" ::: "memory");
    __builtin_amdgcn_s_barrier();
    __builtin_amdgcn_sched_barrier(0);

    int b0 = 0, b1 = 1, b2 = 2;
    for (int t = 0; t < NST; ++t) {
        if (t + 2 < NST) {
#pragma unroll
            for (int i = 0; i < 4; ++i)
                gl_lds16(gsrc[i], ldst[i] + b2 * bstride);
#pragma unroll
            for (int i = 0; i < 4; ++i) gsrc[i] += 32;
        }
        const unsigned short* Ab  = &As[0][0]  + b0 * (128 * 32);
        const unsigned short* B1b = &B1s[0][0] + b0 * (64 * 32);
        const unsigned short* B2b = &B2s[0][0] + b0 * (64 * 32);

        bf16x8 af[4], b1f[2], b2f[2];
#pragma unroll
        for (int mi = 0; mi < 4; ++mi)
            af[mi] = *(const bf16x8*)&Ab[(wm * 64 + mi * 16 + lrow) * 32 + ksw];
#pragma unroll
        for (int ni = 0; ni < 2; ++ni) {
            b1f[ni] = *(const bf16x8*)&B1b[(wn * 32 + ni * 16 + lrow) * 32 + ksw];
            b2f[ni] = *(const bf16x8*)&B2b[(wn * 32 + ni * 16 + lrow) * 32 + ksw];
        }
        __builtin_amdgcn_s_setprio(1);
#pragma unroll
        for (int mi = 0; mi < 4; ++mi)
#pragma unroll
            for (int ni = 0; ni < 2; ++ni) {
                acc1[mi][ni] = __builtin_amdgcn_mfma_f32_16x16x32_bf16(
                    af[mi], b1f[ni], acc1[mi][ni], 0, 0, 0);
                acc2[mi][ni] = __builtin_amdgcn_mfma_f32_16x16x32_bf16(
                    af[mi], b2f[ni], acc2[mi][ni], 0, 0, 0);
            }
        __builtin_amdgcn_s_setprio(0);

        if (t + 1 < NST) {
            if (t + 2 < NST)
                asm volatile("s_waitcnt vmcnt(4)" ::: "memory");  // t+1 landed
            else
                asm volatile("s_waitcnt vmcnt(0)" ::: "memory");  // drain last
            __builtin_amdgcn_s_barrier();
            __builtin_amdgcn_sched_barrier(0);
        }
        int tmp = b0; b0 = b1; b1 = b2; b2 = tmp;
    }

    // epilogue: h = silu(a1) * a3 -> bf16 h_ws[slot, n]
#pragma unroll
    for (int mi = 0; mi < 4; ++mi) {
#pragma unroll
        for (int r = 0; r < 4; ++r) {
            int mloc = wm * 64 + mi * 16 + quad * 4 + r;
            int slot = slots_s[mloc];
            if (slot >= 0) {
                unsigned short* hrow =
                    h_ws + (size_t)slot * HID + n0 + wn * 32 + lrow;
#pragma unroll
                for (int ni = 0; ni < 2; ++ni) {
                    float a1 = acc1[mi][ni][r], a3 = acc2[mi][ni][r];
                    float hv = (a1 / (1.f + __expf(-a1))) * a3;
                    hrow[ni * 16] = (unsigned short)(f2bf_u(hv) >> 16);
                }
            }
        }
    }
}

// ---------------------------------------------------------------------------
// Kernel 3: gathered GEMM y = h @ w2^T, scale by routing weight, PLAIN STORE
// into per-slot y_ws (no atomics: each (slot, col) owned by exactly one
// lane). C-tile 128 x 128, r5 swizzle + depth-2 pipeline.
// grid (DIM/128=8, ceilT/128, NEXP).
// ---------------------------------------------------------------------------
__global__ __launch_bounds__(256) void ffn2_k(
    const unsigned short* __restrict__ h_ws, const unsigned short* __restrict__ w2b,
    const int* __restrict__ cnt, const int* __restrict__ slot_list,
    const float* __restrict__ slot_w, float* __restrict__ y_ws)
{
    __shared__ unsigned short As[3][128 * 32];
    __shared__ unsigned short Bs[3][128 * 32];
    __shared__ int slots_s[128];
    __shared__ float wgt_s[128];

    const int e = blockIdx.z;
    const int cntE = cnt[e];
    const int m0 = blockIdx.y * 128;
    if (m0 >= cntE) return;
    const int n0 = blockIdx.x * 128;
    const int tid = threadIdx.x;
    const int wave = tid >> 6, lane = tid & 63;

    if (tid < 128) {
        int idx = m0 + tid;
        int s = (idx < cntE) ? slot_list[e * T_TOK + idx] : -1;
        slots_s[tid] = s;
        wgt_s[tid] = (s >= 0) ? slot_w[s] : 0.f;
    }
    __syncthreads();

    // staging: waves 0,1 -> A (gathered h rows); waves 2,3 -> w2 rows.
    const int rr = lane >> 2;
    const int qsw = (lane & 3) ^ ((rr >> 1) & 3);
    const unsigned short* gsrc[4];
    unsigned short* ldst[4];
    const int bstride = 128 * 32;
    if (wave < 2) {
#pragma unroll
        for (int i = 0; i < 4; ++i) {
            int row = wave * 64 + i * 16 + rr;
            int slot = slots_s[row];
            int s = (slot >= 0) ? slot : 0;
            gsrc[i] = h_ws + (size_t)s * HID + qsw * 8;
            ldst[i] = &As[0][(wave * 64 + i * 16) * 32];
        }
    } else {
#pragma unroll
        for (int i = 0; i < 4; ++i) {
            int row = (wave - 2) * 64 + i * 16 + rr;
            gsrc[i] = w2b + ((size_t)e * DIM + n0 + row) * HID + qsw * 8;
            ldst[i] = &Bs[0][((wave - 2) * 64 + i * 16) * 32];
        }
    }

    const int wm = wave >> 1, wn = wave & 1;
    const int lrow = lane & 15, quad = lane >> 4;
    const int ksw = (quad ^ ((lrow >> 1) & 3)) * 8;

    f32x4 acc[4][4];
    const f32x4 zf = {0.f, 0.f, 0.f, 0.f};
#pragma unroll
    for (int mi = 0; mi < 4; ++mi)
#pragma unroll
        for (int ni = 0; ni < 4; ++ni) acc[mi][ni] = zf;

    const int NST = HID / 32;   // 88 k-steps
#pragma unroll
    for (int i = 0; i < 4; ++i) gl_lds16(gsrc[i], ldst[i]);
#pragma unroll
    for (int i = 0; i < 4; ++i) gl_lds16(gsrc[i] + 32, ldst[i] + bstride);
#pragma unroll
    for (int i = 0; i < 4; ++i) gsrc[i] += 64;
    asm volatile("s_waitcnt vmcnt(4)" ::: "memory");
    __builtin_amdgcn_s_barrier();
    __builtin_amdgcn_sched_barrier(0);

    int b0 = 0, b1 = 1, b2 = 2;
    for (int t = 0; t < NST; ++t) {
        if (t + 2 < NST) {
#pragma unroll
            for (int i = 0; i < 4; ++i)
                gl_lds16(gsrc[i], ldst[i] + b2 * bstride);
#pragma unroll
            for (int i = 0; i < 4; ++i) gsrc[i] += 32;
        }
        const unsigned short* Ab = &As[0][0] + b0 * bstride;
        const unsigned short* Bb = &Bs[0][0] + b0 * bstride;

        bf16x8 af[4], bf[4];
#pragma unroll
        for (int mi = 0; mi < 4; ++mi)
            af[mi] = *(const bf16x8*)&Ab[(wm * 64 + mi * 16 + lrow) * 32 + ksw];
#pragma unroll
        for (int ni = 0; ni < 4; ++ni)
            bf[ni] = *(const bf16x8*)&Bb[(wn * 64 + ni * 16 + lrow) * 32 + ksw];
        __builtin_amdgcn_s_setprio(1);
#pragma unroll
        for (int mi = 0; mi < 4; ++mi)
#pragma unroll
            for (int ni = 0; ni < 4; ++ni)
                acc[mi][ni] = __builtin_amdgcn_mfma_f32_16x16x32_bf16(
                    af[mi], bf[ni], acc[mi][ni], 0, 0, 0);
        __builtin_amdgcn_s_setprio(0);

        if (t + 1 < NST) {
            if (t + 2 < NST)
                asm volatile("s_waitcnt vmcnt(4)" ::: "memory");
            else
                asm volatile("s_waitcnt vmcnt(0)" ::: "memory");
            __builtin_amdgcn_s_barrier();
            __builtin_amdgcn_sched_barrier(0);
        }
        int tmp = b0; b0 = b1; b1 = b2; b2 = tmp;
    }

    // epilogue: plain stores, one owner per (slot, col).
#pragma unroll
    for (int mi = 0; mi < 4; ++mi) {
#pragma unroll
        for (int r = 0; r < 4; ++r) {
            int mloc = wm * 64 + mi * 16 + quad * 4 + r;
            int slot = slots_s[mloc];
            if (slot >= 0) {
                float w = wgt_s[mloc];
                float* yrow = y_ws + (size_t)slot * DIM + n0 + wn * 64 + lrow;
#pragma unroll
                for (int ni = 0; ni < 4; ++ni)
                    yrow[ni * 16] = acc[mi][ni][r] * w;
            }
        }
    }
}

// ---------------------------------------------------------------------------
// Kernel 4: combine. out[t] = y[2t] + y[2t+1]  (both already weight-scaled).
// 8192 tokens x 256 float4.
// ---------------------------------------------------------------------------
__global__ __launch_bounds__(256) void combine_k(
    const float* __restrict__ y, float* __restrict__ out)
{
    int i = blockIdx.x * 256 + threadIdx.x;      // i in [0, 8192*256)
    int t = i >> 8, d = i & 255;
    const float4* a = (const float4*)(y + (size_t)(2 * t) * DIM) + d;
    const float4* b = (const float4*)(y + (size_t)(2 * t + 1) * DIM) + d;
    float4 va = *a, vb = *b;
    float4 o = {va.x + vb.x, va.y + vb.y, va.z + vb.z, va.w + vb.w};
    ((float4*)(out + (size_t)t * DIM))[d] = o;
}

// ---------------------------------------------------------------------------
// Workspace layout (bytes):
//   [0, 256)                 cnt[8]                (memset 0 per launch)
//   [256, +262144)           slot_list[8][8192]
//   [+262144, +65536)        slot_w[16384]
//   [327936, +92274688)      h_ws   bf16 [16384][2816]
//   [92602624, +16777216)    x_bf   bf16 [8192][1024]
//   [109379840, +46137344)   w1_bf  bf16 [8][2816][1024]
//   [155517184, +46137344)   w3_bf
//   [201654528, +46137344)   w2_bf  bf16 [8][1024][2816]
//   y_ws f32 [16384][1024] = 67108864 B ALIASES [92602624, 159711488):
//   x_bf + w1_bf + first 4.2MB of w3_bf — all dead after ffn1 completes;
//   stream order (ffn1 -> ffn2 -> combine -> next-iter cvt) makes this safe.
// ---------------------------------------------------------------------------
extern "C" void kernel_launch(void* const* d_in, const int* in_sizes, int n_in,
                              void* d_out, int out_size, void* d_ws, size_t ws_size,
                              hipStream_t stream) {
    const float* x  = (const float*)d_in[0];
    const float* gw = (const float*)d_in[1];
    const float* w1 = (const float*)d_in[2];
    const float* w2 = (const float*)d_in[3];
    const float* w3 = (const float*)d_in[4];
    float* out = (float*)d_out;

    char* ws = (char*)d_ws;
    int*   cnt       = (int*)ws;
    int*   slot_list = (int*)(ws + 256);
    float* slot_w    = (float*)(ws + 256 + NEXP * T_TOK * 4);
    unsigned short* h_ws = (unsigned short*)(ws + 327936);
    unsigned short* x_bf = (unsigned short*)(ws + 92602624);
    unsigned short* w1_bf = (unsigned short*)(ws + 109379840);
    unsigned short* w3_bf = (unsigned short*)(ws + 155517184);
    unsigned short* w2_bf = (unsigned short*)(ws + 201654528);
    float* y_ws = (float*)(ws + 92602624);   // aliases x_bf/w1_bf (dead post-ffn1)

    hipMemsetAsync(cnt, 0, 256, stream);

    const int nx = T_TOK * DIM / 8;              // 1048576
    const int nw = NEXP * HID * DIM / 8;         // 2883584
    cvt_k<<<(nx + 255) / 256, 256, 0, stream>>>(x, x_bf, nx);
    cvt_k<<<(nw + 255) / 256, 256, 0, stream>>>(w1, w1_bf, nw);
    cvt_k<<<(nw + 255) / 256, 256, 0, stream>>>(w3, w3_bf, nw);
    cvt_k<<<(nw + 255) / 256, 256, 0, stream>>>(w2, w2_bf, nw);

    router_k<<<T_TOK / 4, 256, 0, stream>>>(x, gw, cnt, slot_list, slot_w);
    ffn1_k<<<dim3(HID / 64, T_TOK / 128, NEXP), 256, 0, stream>>>(
        x_bf, w1_bf, w3_bf, cnt, slot_list, h_ws);
    ffn2_k<<<dim3(DIM / 128, T_TOK / 128, NEXP), 256, 0, stream>>>(
        h_ws, w2_bf, cnt, slot_list, slot_w, y_ws);
    combine_k<<<T_TOK, 256, 0, stream>>>(y_ws, out);
}